// Round 17
// baseline (294.873 us; speedup 1.0000x reference)
//
#include <hip/hip_runtime.h>
#include <hip/hip_bf16.h>

#define B_ 128
#define T_ 512
#define N_ 256
#define H_ 1024

typedef unsigned short u16;
typedef __attribute__((ext_vector_type(8))) __bf16 bf16x8;
typedef __attribute__((ext_vector_type(4))) float f32x4;

__device__ __forceinline__ u16 f2bf(float f) {
    unsigned u = __float_as_uint(f);
    u = (u + 0x7FFFu + ((u >> 16) & 1u)) >> 16;
    return (u16)u;
}

__device__ __forceinline__ void g2l16(const void* g, void* l) {
    __builtin_amdgcn_global_load_lds(
        (const __attribute__((address_space(1))) void*)g,
        (__attribute__((address_space(3))) void*)l,
        16, 0, 0);
}

// ===========================================================================
// R17 "e4" engine: 128x128 tile, 4 waves (2x2 of the proven 64x64 wave tile),
// BK=32, 2-slot LDS ring (32 KiB) -> 4 blocks/CU, 16 waves/CU.
// R9-proven schedule: GATE(0) per tile, stage 1 tile ahead. Same verified
// swizzle involution. OUT==0 direct bf16, OUT==1 direct nontemporal f32,
// OUT==2 two-pass LDS-staged transposed q-write.
// ===========================================================================
#define ASLOT 8192u   // u16 per ring slot: A[128][32] (4096) + B[128][32] (4096)

#define GATE(N) { asm volatile("s_waitcnt vmcnt(" #N ")" ::: "memory"); \
                  __builtin_amdgcn_s_barrier(); }
#define LD4(dst, base) { _Pragma("unroll") for (int i_ = 0; i_ < 4; ++i_) \
    dst[i_] = *(const bf16x8*)(L + (base) + i_ * 512); }
#define STAGE(tile) { const u16* a_ = gA + (size_t)(tile) * 32; \
    const u16* b_ = gB + (size_t)(tile) * 32; \
    const unsigned s_ = (unsigned)(((tile) & 1) * ASLOT); \
    g2l16(a_, dA0 + s_);  g2l16(a_ + rstr, dA0 + s_ + 2048); \
    g2l16(b_, dB0 + s_);  g2l16(b_ + rstr, dB0 + s_ + 2048); }

template<int ACT, int OUT>
__global__ __launch_bounds__(256, 4) void gemm_e4(
    const u16* __restrict__ A, const u16* __restrict__ Bt,
    float* __restrict__ Cf, u16* __restrict__ Cb,
    const float* __restrict__ bias,
    int Nc, int K, int bshift, int gysh)
{
    __shared__ u16 L[16384];   // 32 KiB
    const int tid = threadIdx.x;
    const int wave = tid >> 6, lane = tid & 63;
    const int l16 = lane & 15, lh = lane >> 4;
    const int wm = wave >> 1, wn = wave & 1;   // 2x2 wave grid, 64x64 each

    // bijective XCD swizzle (all grids are multiples of 8)
    const int qq = (int)gridDim.x >> 3;
    const int orig = (int)blockIdx.x;
    const int wg = (orig & 7) * qq + (orig >> 3);
    const int by = wg & ((1 << gysh) - 1), bx = wg >> gysh;
    const size_t m0 = (size_t)bx * 128, n0 = (size_t)by * 128;

    // read-side swizzled fragment offsets (16B slot ^= (row>>1)&3)
    const int sx8 = (lh ^ ((l16 >> 1) & 3)) * 8;
    const unsigned aoff = (unsigned)(wm * 2048 + l16 * 32 + sx8);
    const unsigned boff = (unsigned)(4096 + wn * 2048 + l16 * 32 + sx8);

    // staging: thread covers rows tid>>2 and +64; 16B chunk tid&3, pre-swz src
    const int srow = tid >> 2;                          // 0..63
    const int sslot = (tid & 3) ^ ((srow >> 1) & 3);    // same for row+64
    const size_t rstr = (size_t)64 * K;
    const u16* gA = A + (m0 + srow) * (size_t)K + sslot * 8;
    const u16* gB = Bt + (n0 + srow) * (size_t)K + sslot * 8;
    u16* const dA0 = L + (unsigned)(wave * 512);
    u16* const dB0 = L + 4096 + (unsigned)(wave * 512);

    f32x4 acc[4][4] = {};
    const int nt = K >> 5;

    STAGE(0);
    for (int t = 0; t < nt; ++t) {
        GATE(0);   // tile t landed
        const unsigned sl = (unsigned)((t & 1) * ASLOT);
        bf16x8 ra[4], rb[4];
        LD4(ra, sl + aoff);
        LD4(rb, sl + boff);
        if (t + 1 < nt) STAGE(t + 1);
        __builtin_amdgcn_s_setprio(1);
#pragma unroll
        for (int mi = 0; mi < 4; ++mi)
#pragma unroll
            for (int ni = 0; ni < 4; ++ni)
                acc[mi][ni] = __builtin_amdgcn_mfma_f32_16x16x32_bf16(
                    ra[mi], rb[ni], acc[mi][ni], 0, 0, 0);
        __builtin_amdgcn_s_setprio(0);
    }

    const size_t NcS = (size_t)Nc;
    if (OUT == 2) {
        // --- transposed q-write via LDS, two 64-t passes (fits 32 KiB) ---
        const int P = 132;                 // u16 pitch; 264B rows (8B-aligned)
        const size_t b = m0 >> 8;
        const int nb = (int)(m0 & 255);
        __syncthreads();                   // ring readers done
#pragma unroll
        for (int p = 0; p < 2; ++p) {
            if (wn == p) {
#pragma unroll
                for (int mi = 0; mi < 4; ++mi) {
#pragma unroll
                    for (int ni = 0; ni < 4; ++ni) {
                        int tt = ni * 16 + l16;            // 0..63 within pass
                        int nn = wm * 64 + mi * 16 + lh * 4;
                        u16 e[4];
#pragma unroll
                        for (int rr = 0; rr < 4; ++rr) {
                            float v = acc[mi][ni][rr];
                            v = 1.0f / (1.0f + __expf(-v));
                            e[rr] = f2bf(v);
                        }
                        *(uint2*)&L[tt * P + nn] = *(const uint2*)e;
                    }
                }
            }
            __syncthreads();
            const int tp = tid >> 2, seg = tid & 3;        // 64 rows x 4 segs
            const u16* src = &L[tp * P + seg * 32];
            u16* dst = Cb + ((b * T_ + (n0 + p * 64 + (size_t)tp)) * N_ + nb + seg * 32);
#pragma unroll
            for (int i = 0; i < 4; ++i)
                ((uint4*)dst)[i] = *(const uint4*)&src[i * 8];
            __syncthreads();
        }
    } else {
        // direct per-lane stores (64B segments per 16-lane group — coalesced)
#pragma unroll
        for (int mi = 0; mi < 4; ++mi) {
#pragma unroll
            for (int ni = 0; ni < 4; ++ni) {
                size_t rbase = m0 + wm * 64 + mi * 16 + lh * 4;
                size_t col   = n0 + wn * 64 + ni * 16 + l16;
#pragma unroll
                for (int rr = 0; rr < 4; ++rr) {
                    size_t row = rbase + rr;
                    float v = acc[mi][ni][rr];
                    if (bias) v += bias[(row >> bshift) * NcS + col];
                    if (ACT) v = 1.0f / (1.0f + __expf(-v));
                    if (OUT == 1) __builtin_nontemporal_store(v, &Cf[row * NcS + col]);
                    else          Cb[row * NcS + col] = f2bf(v);
                }
            }
        }
    }
}

// ---------------------------------------------------------------------------
// 128x128 2-barrier GEMM body (device fn) for small GEMMs.
// outmode: 0 bf16, 1 f32, 2 dual-concat bf16, 3 f32 atomicAdd (split-K).
// ---------------------------------------------------------------------------
__device__ __forceinline__ void small_body(
    const u16* __restrict__ A, const u16* __restrict__ Bt,
    float* __restrict__ Cf, u16* __restrict__ Cb,
    const float* __restrict__ bias,
    int Nc, int K, int lda, int ldb, int outmode, int bshift,
    float kscale, float bmul, int bx, int by)
{
    __shared__ u16 lA[128 * 64];
    __shared__ u16 lB[128 * 64];
    const int tid = threadIdx.x;
    const int wave = tid >> 6, lane = tid & 63;
    const int l16 = lane & 15, lh = lane >> 4;
    const int wm = wave >> 1, wn = wave & 1;
    const long m0 = (long)bx * 128;
    const long n0 = (long)by * 128;

    f32x4 acc[4][4] = {};

    for (int k0 = 0; k0 < K; k0 += 64) {
#pragma unroll
        for (int j = 0; j < 4; ++j) {
            int c = j * 256 + tid;
            int row = c >> 3, col = (c & 7) << 3;
            g2l16(A  + (m0 + row) * (size_t)lda + k0 + col, &lA[(size_t)(j * 256 + (wave << 6)) * 8]);
            g2l16(Bt + (n0 + row) * (size_t)ldb + k0 + col, &lB[(size_t)(j * 256 + (wave << 6)) * 8]);
        }
        __syncthreads();
#pragma unroll
        for (int s = 0; s < 2; ++s) {
            bf16x8 af[4], bfr[4];
#pragma unroll
            for (int mi = 0; mi < 4; ++mi)
                af[mi] = *(const bf16x8*)&lA[((wm << 6) + (mi << 4) + l16) * 64 + s * 32 + (lh << 3)];
#pragma unroll
            for (int ni = 0; ni < 4; ++ni)
                bfr[ni] = *(const bf16x8*)&lB[((wn << 6) + (ni << 4) + l16) * 64 + s * 32 + (lh << 3)];
#pragma unroll
            for (int mi = 0; mi < 4; ++mi)
#pragma unroll
                for (int ni = 0; ni < 4; ++ni)
                    acc[mi][ni] = __builtin_amdgcn_mfma_f32_16x16x32_bf16(af[mi], bfr[ni], acc[mi][ni], 0, 0, 0);
        }
        __syncthreads();
    }

#pragma unroll
    for (int mi = 0; mi < 4; ++mi) {
#pragma unroll
        for (int ni = 0; ni < 4; ++ni) {
            long rbase = m0 + (wm << 6) + (mi << 4) + (lh << 2);
            long col   = n0 + (wn << 6) + (ni << 4) + l16;
#pragma unroll
            for (int r = 0; r < 4; ++r) {
                long row = rbase + r;
                float v = acc[mi][ni][r] * kscale;
                if (outmode == 2) {
                    v += (col < 1024 ? 1.0f : 256.0f / 255.0f) * bias[col & 1023];
                    Cb[(size_t)row * Nc + col] = f2bf(v);
                } else if (outmode == 3) {
                    if (bias) v += bmul * bias[(size_t)(row >> bshift) * Nc + col];
                    atomicAdd(&Cf[(size_t)row * Nc + col], v);
                } else {
                    if (bias) v += bmul * bias[(size_t)(row >> bshift) * Nc + col];
                    if (outmode == 1) Cf[(size_t)row * Nc + col] = v;
                    else              Cb[(size_t)row * Nc + col] = f2bf(v);
                }
            }
        }
    }
}

// S23 split-K: grid (8 k-chunks, 8 col-blocks); t12 += Acat[:,kc]@W2cat[:,kc]^T
// (+ b2 on k-chunk 0). t12 zero-initialized via hipMemsetAsync.
__global__ __launch_bounds__(256) void gemm_s23(
    const u16* __restrict__ Acat, const u16* __restrict__ W2cat,
    float* __restrict__ t12, const float* __restrict__ b2)
{
    small_body(Acat + blockIdx.x * 256, W2cat + blockIdx.x * 256, t12, nullptr,
               blockIdx.x == 0 ? b2 : nullptr,
               1024, 256, 2048, 2048, 3, 31, 1.0f, 1.0f, 0, blockIdx.y);
}

// Four independent small GEMMs in one launch (96 blocks)
__global__ __launch_bounds__(256) void k_small4(
    const u16* __restrict__ W2cat, const u16* __restrict__ W1rm, u16* __restrict__ W12t,
    const u16* __restrict__ W1bt, const u16* __restrict__ W1ab, u16* __restrict__ W1ct,
    const u16* __restrict__ W2bt, const u16* __restrict__ W2ab, u16* __restrict__ W2ct,
    const u16* __restrict__ s1b, const u16* __restrict__ Wcat, u16* __restrict__ Acat,
    const float* __restrict__ b1)
{
    const int bid = blockIdx.x;
    if (bid < 32) {
        small_body(W2cat, W1rm, nullptr, W12t, nullptr, 512, 1024, 2048, 1024,
                   0, 0, 1.0f, 0.0f, bid >> 2, bid & 3);
    } else if (bid < 64) {
        int r = bid - 32;
        small_body(W1bt, W1ab, nullptr, W1ct, nullptr, 1024, 1024, 1024, 1024,
                   0, 0, 1.0f, 0.0f, r >> 3, r & 7);
    } else if (bid < 80) {
        int r = bid - 64;
        small_body(W2bt, W2ab, nullptr, W2ct, nullptr, 256, 256, 256, 256,
                   0, 0, 1.0f, 0.0f, r >> 1, r & 1);
    } else {
        int r = bid - 80;
        small_body(s1b, Wcat, nullptr, Acat, b1, 2048, 512, 512, 512,
                   2, 0, 1.0f / 255.0f, 0.0f, 0, r);
    }
}

// ---------------------------------------------------------------------------
// Merged prep: weight transforms (blocks 0..2847) + x transpose/rowsum
// (blocks 2848..4895), one launch, all (32,8) = 256 threads.
// ---------------------------------------------------------------------------
__global__ __launch_bounds__(256) void k_prep(
    const float* __restrict__ Wl1, const float* __restrict__ Wr1,
    const float* __restrict__ Wl2, const float* __restrict__ Wr2,
    const float* __restrict__ W1b, const float* __restrict__ W2b,
    const float* __restrict__ W1a, const float* __restrict__ W2a,
    u16* __restrict__ Wcat, u16* __restrict__ W1rm,
    u16* __restrict__ W2cat,
    u16* __restrict__ W1bt, u16* __restrict__ W2bt,
    u16* __restrict__ W1ab, u16* __restrict__ W2ab,
    const float* __restrict__ x, u16* __restrict__ h, u16* __restrict__ s1b)
{
    __shared__ float smem[32 * 257];
    int bid = blockIdx.x;
    const int tx = threadIdx.x, ty = threadIdx.y;
    if (bid < 512) {
        float (*tl)[33] = (float(*)[33])smem;
        float (*tr)[33] = (float(*)[33])(smem + 32 * 33);
        int r0 = (bid >> 5) * 32, c0 = (bid & 31) * 32;
#pragma unroll
        for (int i = 0; i < 4; ++i) {
            int r = r0 + ty + 8 * i;
            float wl = Wl1[(size_t)r * H_ + c0 + tx];
            float wr = Wr1[(size_t)r * H_ + c0 + tx];
            tl[ty + 8 * i][tx] = wl;
            tr[ty + 8 * i][tx] = wl + wr;
            W1rm[(size_t)r * H_ + c0 + tx] = f2bf(wr - wl * (1.0f / 255.0f));
        }
        __syncthreads();
#pragma unroll
        for (int i = 0; i < 4; ++i) {
            size_t o = (size_t)(c0 + ty + 8 * i) * T_ + r0 + tx;
            Wcat[o]                     = f2bf(tl[tx][ty + 8 * i]);
            Wcat[o + (size_t)1024 * T_] = f2bf(tr[tx][ty + 8 * i]);
        }
    } else if (bid < 1536) {
        float (*tl)[33] = (float(*)[33])smem;
        float (*tr)[33] = (float(*)[33])(smem + 32 * 33);
        bid -= 512;
        int r0 = (bid >> 5) * 32, c0 = (bid & 31) * 32;
#pragma unroll
        for (int i = 0; i < 4; ++i) {
            int r = r0 + ty + 8 * i;
            float wl = Wl2[(size_t)r * H_ + c0 + tx];
            float wr = Wr2[(size_t)r * H_ + c0 + tx];
            tl[ty + 8 * i][tx] = wr - wl * (1.0f / 255.0f);
            tr[ty + 8 * i][tx] = wl;
        }
        __syncthreads();
#pragma unroll
        for (int i = 0; i < 4; ++i) {
            size_t o = (size_t)(c0 + ty + 8 * i) * 2048 + r0 + tx;
            W2cat[o]        = f2bf(tl[tx][ty + 8 * i]);
            W2cat[o + 1024] = f2bf(tr[tx][ty + 8 * i]);
        }
    } else if (bid < 2048) {
        float (*tl)[33] = (float(*)[33])smem;
        bid -= 1536;
        int r0 = (bid >> 4) * 32, c0 = (bid & 15) * 32;
#pragma unroll
        for (int i = 0; i < 4; ++i)
            tl[ty + 8 * i][tx] = W1b[(size_t)(r0 + ty + 8 * i) * T_ + c0 + tx];
        __syncthreads();
#pragma unroll
        for (int i = 0; i < 4; ++i)
            W1bt[(size_t)(c0 + ty + 8 * i) * H_ + r0 + tx] = f2bf(tl[tx][ty + 8 * i]);
    } else if (bid < 2304) {
        float (*tl)[33] = (float(*)[33])smem;
        bid -= 2048;
        int r0 = (bid >> 5) * 32, c0 = (bid & 31) * 32;
#pragma unroll
        for (int i = 0; i < 4; ++i)
            tl[ty + 8 * i][tx] = W2b[(size_t)(r0 + ty + 8 * i) * H_ + c0 + tx];
        __syncthreads();
#pragma unroll
        for (int i = 0; i < 4; ++i)
            W2bt[(size_t)(c0 + ty + 8 * i) * N_ + r0 + tx] = f2bf(tl[tx][ty + 8 * i]);
    } else if (bid < 2848) {
        int i = (bid - 2304) * 256 + ty * 32 + tx;
        const int n1 = H_ * H_ / 8;
        const float* s; u16* d;
        if (i < n1) { s = W1a; d = W1ab; }
        else        { s = W2a; d = W2ab; i -= n1; }
        float4 a = ((const float4*)s)[2 * i], b = ((const float4*)s)[2 * i + 1];
        u16 e[8] = {f2bf(a.x), f2bf(a.y), f2bf(a.z), f2bf(a.w),
                    f2bf(b.x), f2bf(b.y), f2bf(b.z), f2bf(b.w)};
        ((uint4*)d)[i] = *(const uint4*)e;
    } else {
        float (*sm)[257] = (float(*)[257])smem;
        int bid2 = bid - 2848;
        const int b = bid2 >> 4, t0 = (bid2 & 15) * 32;
        const int tid = ty * 32 + tx;
        const int wave = tid >> 6, lane = tid & 63;
        const float* xb = x + ((size_t)b * T_ + t0) * N_;
#pragma unroll
        for (int i = 0; i < 8; ++i) {
            int j = wave * 8 + i;
            float4 v = *(const float4*)(xb + (size_t)j * N_ + lane * 4);
            sm[j][lane * 4 + 0] = v.x;
            sm[j][lane * 4 + 1] = v.y;
            sm[j][lane * 4 + 2] = v.z;
            sm[j][lane * 4 + 3] = v.w;
        }
        __syncthreads();
#pragma unroll
        for (int i = 0; i < 8; ++i) {
            int j = wave * 8 + i;
            float s = sm[j][lane] + sm[j][lane + 64] + sm[j][lane + 128] + sm[j][lane + 192];
#pragma unroll
            for (int o = 32; o; o >>= 1) s += __shfl_down(s, o, 64);
            if (lane == 0) s1b[(size_t)b * T_ + t0 + j] = f2bf(s);
        }
        u16 e[32];
#pragma unroll
        for (int j = 0; j < 32; ++j) e[j] = f2bf(sm[j][tid]);
        uint4* dst = (uint4*)(h + ((size_t)b * N_ + tid) * T_ + t0);
        const uint4* src = (const uint4*)e;
#pragma unroll
        for (int v = 0; v < 4; ++v) dst[v] = src[v];
    }
}

extern "C" void kernel_launch(void* const* d_in, const int* in_sizes, int n_in,
                              void* d_out, int out_size, void* d_ws, size_t ws_size,
                              hipStream_t stream)
{
    const float* x   = (const float*)d_in[0];
    const float* Wl1 = (const float*)d_in[1];
    const float* Wr1 = (const float*)d_in[2];
    const float* b1  = (const float*)d_in[3];
    const float* Wl2 = (const float*)d_in[4];
    const float* Wr2 = (const float*)d_in[5];
    const float* b2  = (const float*)d_in[6];
    const float* W1a = (const float*)d_in[7];
    const float* W1b = (const float*)d_in[8];
    const float* W2a = (const float*)d_in[9];
    const float* W2b = (const float*)d_in[10];
    float* out = (float*)d_out;

    char* ws = (char*)d_ws;
    size_t off = 0;
    auto alloc = [&](size_t bytes) -> char* {
        char* p = ws + off;
        off += (bytes + 255) & ~(size_t)255;
        return p;
    };

    const size_t BN = (size_t)B_ * N_;   // 32768
    const size_t BT = (size_t)B_ * T_;   // 65536

    u16* h_bf   = (u16*)alloc(BN * T_ * 2);              // h, later q
    u16* h2_bf  = (u16*)alloc(BN * H_ * 2);
    u16* Wcat   = (u16*)alloc((size_t)2048 * T_ * 2);    // [Wl1t ; Wlr1t]
    u16* W1rm   = (u16*)alloc((size_t)T_ * H_ * 2);
    u16* W2cat  = (u16*)alloc((size_t)H_ * 2048 * 2);    // [W2'^T | Wl2^T]
    u16* W1bt   = (u16*)alloc((size_t)T_ * H_ * 2);
    u16* W1ab   = (u16*)alloc((size_t)H_ * H_ * 2);
    u16* W1ct   = (u16*)alloc((size_t)T_ * H_ * 2);
    u16* W2bt   = (u16*)alloc((size_t)H_ * N_ * 2);
    u16* W2ab   = (u16*)alloc((size_t)N_ * N_ * 2);
    u16* W2ct   = (u16*)alloc((size_t)H_ * N_ * 2);
    u16* W12t   = (u16*)alloc((size_t)H_ * T_ * 2);
    u16* s1b    = (u16*)alloc(BT * 2);
    u16* Acat   = (u16*)alloc((size_t)B_ * 2048 * 2);    // [t1b1 | u1s]
    float* t12  = (float*)alloc((size_t)B_ * H_ * 4);

    u16* q_bf = h_bf;

    // --- prep ---
    hipMemsetAsync(t12, 0, (size_t)B_ * H_ * 4, stream);
    k_prep<<<dim3(4896), dim3(32, 8), 0, stream>>>(Wl1, Wr1, Wl2, Wr2, W1b, W2b, W1a, W2a,
                                                   Wcat, W1rm, W2cat, W1bt, W2bt, W1ab, W2ab,
                                                   x, h_bf, s1b);
    k_small4<<<dim3(96), 256, 0, stream>>>(W2cat, W1rm, W12t, W1bt, W1ab, W1ct,
                                           W2bt, W2ab, W2ct, s1b, Wcat, Acat, b1);
    // S23 split-K: t12 += sum_kc Acat[:,kc]@W2cat[:,kc]^T (+ b2 on kc 0)
    gemm_s23<<<dim3(8, 8), 256, 0, stream>>>(Acat, W2cat, t12, b2);

    // --- main chain (3 e4 GEMMs; 4 blocks/CU) ---
    // GA: h2 = h @ W12 + t12   [32768,1024] K=512 -> 256x8 = 2048 wgs
    gemm_e4<0, 0><<<dim3(2048), 256, 0, stream>>>(h_bf, W12t, nullptr, h2_bf, t12, H_, T_, 8, 3);
    // GB: q = sigma(h2 @ W1c) transposed q[B,T,N]   K=1024 -> 256x4 = 1024 wgs
    gemm_e4<1, 2><<<dim3(1024), 256, 0, stream>>>(h2_bf, W1ct, nullptr, q_bf, nullptr, T_, H_, 0, 2);
    // GC: out = sigma(q @ W2c) f32, nt stores   K=256 -> 512x8 = 4096 wgs
    gemm_e4<1, 1><<<dim3(4096), 256, 0, stream>>>(q_bf, W2ct, out, nullptr, nullptr, H_, N_, 0, 3);
}

// Round 18
// 270.588 us; speedup vs baseline: 1.0897x; 1.0897x over previous
//
#include <hip/hip_runtime.h>
#include <hip/hip_bf16.h>

#define B_ 128
#define T_ 512
#define N_ 256
#define H_ 1024

typedef unsigned short u16;
typedef __attribute__((ext_vector_type(8))) __bf16 bf16x8;
typedef __attribute__((ext_vector_type(4))) float f32x4;

__device__ __forceinline__ u16 f2bf(float f) {
    unsigned u = __float_as_uint(f);
    u = (u + 0x7FFFu + ((u >> 16) & 1u)) >> 16;
    return (u16)u;
}

__device__ __forceinline__ void g2l16(const void* g, void* l) {
    __builtin_amdgcn_global_load_lds(
        (const __attribute__((address_space(1))) void*)g,
        (__attribute__((address_space(3))) void*)l,
        16, 0, 0);
}

// ===========================================================================
// R18: exact R16 restore (best measured: 271.3 us).
// e3 K-loop (731 TF, 0 bank conflicts, VGPR 72); 256x128 tile, 8 waves of
// 64x64, BK=32, 3-slot ring (72 KiB), 2 blocks/CU; counted gate vmcnt(3).
// OUT==0 direct bf16 stores; OUT==1 nontemporal f32 stores (write-once out);
// OUT==2 LDS-staged transposed q-write.
// ===========================================================================
#define ASLOT 12288u   // u16 per slot: A[256][32] (8192) + B[128][32] (4096)

#define GATE(N) { asm volatile("s_waitcnt vmcnt(" #N ")" ::: "memory"); \
                  __builtin_amdgcn_s_barrier(); }
#define LD4(dst, base) { _Pragma("unroll") for (int i_ = 0; i_ < 4; ++i_) \
    dst[i_] = *(const bf16x8*)(L + (base) + i_ * 512); }
#define STAGE(tile) { const u16* a_ = gA + (size_t)(tile) * 32; \
    const u16* b_ = gB + (size_t)(tile) * 32; \
    const unsigned s_ = (unsigned)(((tile) % 3) * ASLOT); \
    g2l16(a_, dA0 + s_);  g2l16(a_ + jstr, dA0 + s_ + 4096); \
    g2l16(b_, dB0 + s_); }
#define BODY(t) { \
    const unsigned sl = (unsigned)(((t) % 3) * ASLOT); \
    bf16x8 ra[4], rb[4]; \
    LD4(ra, sl + aoff); \
    LD4(rb, sl + boff); \
    if ((t) + 2 < nt) STAGE((t) + 2); \
    __builtin_amdgcn_s_setprio(1); \
    _Pragma("unroll") for (int mi_ = 0; mi_ < 4; ++mi_) \
    _Pragma("unroll") for (int ni_ = 0; ni_ < 4; ++ni_) \
        acc[mi_][ni_] = __builtin_amdgcn_mfma_f32_16x16x32_bf16( \
            ra[mi_], rb[ni_], acc[mi_][ni_], 0, 0, 0); \
    __builtin_amdgcn_s_setprio(0); }

template<int ACT, int OUT>
__global__ __launch_bounds__(512, 2) void gemm_e3(
    const u16* __restrict__ A, const u16* __restrict__ Bt,
    float* __restrict__ Cf, u16* __restrict__ Cb,
    const float* __restrict__ bias,
    int Nc, int K, int bshift, int gysh)
{
    __shared__ u16 L[36864];   // 72 KiB
    const int tid = threadIdx.x;
    const int wave = tid >> 6, lane = tid & 63;
    const int l16 = lane & 15, lh = lane >> 4;
    const int wm = wave >> 1, wn = wave & 1;   // 4x2 wave grid, 64x64 each

    // bijective XCD swizzle (all grids are multiples of 8)
    const int qq = (int)gridDim.x >> 3;
    const int orig = (int)blockIdx.x;
    const int wg = (orig & 7) * qq + (orig >> 3);
    const int by = wg & ((1 << gysh) - 1), bx = wg >> gysh;
    const size_t m0 = (size_t)bx * 256, n0 = (size_t)by * 128;

    // read-side swizzled fragment offsets (16B slot ^= (row>>1)&3)
    const int sx8 = (lh ^ ((l16 >> 1) & 3)) * 8;
    const unsigned aoff = (unsigned)(wm * 2048 + l16 * 32 + sx8);
    const unsigned boff = (unsigned)(8192 + wn * 2048 + l16 * 32 + sx8);

    // staging: thread row tid>>2 (A also +128), 16B chunk tid&3, pre-swz src
    const int srow = tid >> 2;
    const int sslot = (tid & 3) ^ ((srow >> 1) & 3);
    const size_t jstr = (size_t)128 * K;
    const u16* gA = A + (m0 + srow) * (size_t)K + sslot * 8;
    const u16* gB = Bt + (n0 + srow) * (size_t)K + sslot * 8;
    u16* const dA0 = L + (unsigned)(wave * 512);
    u16* const dB0 = L + 8192 + (unsigned)(wave * 512);

    f32x4 acc[4][4] = {};
    const int nt = K >> 5;   // >= 8 for all uses

    STAGE(0); STAGE(1);      // 6 loads in flight
    for (int t = 0; t < nt - 1; ++t) {
        GATE(3);             // tile t landed; tile t+1's 3 stay in flight
        BODY(t);
    }
    GATE(0);                 // last tile
    { const int t = nt - 1; BODY(t); }

    const size_t NcS = (size_t)Nc;
    if (OUT == 2) {
        // --- coalesced transposed q-write via LDS round-trip ---
        __syncthreads();
        const int P = 260;
#pragma unroll
        for (int mi = 0; mi < 4; ++mi) {
#pragma unroll
            for (int ni = 0; ni < 4; ++ni) {
                int tt = wn * 64 + ni * 16 + l16;
                int nn = wm * 64 + mi * 16 + lh * 4;
                u16 e[4];
#pragma unroll
                for (int rr = 0; rr < 4; ++rr) {
                    float v = acc[mi][ni][rr];
                    v = 1.0f / (1.0f + __expf(-v));
                    e[rr] = f2bf(v);
                }
                *(uint2*)&L[tt * P + nn] = *(const uint2*)e;
            }
        }
        __syncthreads();
        const int t = tid >> 2, seg = tid & 3;
        const u16* src = &L[t * P + seg * 64];
        uint2 u2[16];
#pragma unroll
        for (int j = 0; j < 16; ++j) u2[j] = *(const uint2*)&src[j * 4];
        const size_t b = m0 >> 8;
        u16* dst = Cb + ((b * T_ + (n0 + (size_t)t)) * N_ + seg * 64);
#pragma unroll
        for (int i = 0; i < 8; ++i) {
            uint4 w = make_uint4(u2[2 * i].x, u2[2 * i].y, u2[2 * i + 1].x, u2[2 * i + 1].y);
            ((uint4*)dst)[i] = w;
        }
    } else {
        // direct per-lane stores (64B segments per 16-lane group — coalesced)
#pragma unroll
        for (int mi = 0; mi < 4; ++mi) {
#pragma unroll
            for (int ni = 0; ni < 4; ++ni) {
                size_t rbase = m0 + wm * 64 + mi * 16 + lh * 4;
                size_t col   = n0 + wn * 64 + ni * 16 + l16;
#pragma unroll
                for (int rr = 0; rr < 4; ++rr) {
                    size_t row = rbase + rr;
                    float v = acc[mi][ni][rr];
                    if (bias) v += bias[(row >> bshift) * NcS + col];
                    if (ACT) v = 1.0f / (1.0f + __expf(-v));
                    if (OUT == 1) __builtin_nontemporal_store(v, &Cf[row * NcS + col]);
                    else          Cb[row * NcS + col] = f2bf(v);
                }
            }
        }
    }
}

// ---------------------------------------------------------------------------
// 128x128 2-barrier GEMM body (device fn) for small GEMMs.
// outmode: 0 bf16, 1 f32, 2 dual-concat bf16, 3 f32 atomicAdd (split-K).
// ---------------------------------------------------------------------------
__device__ __forceinline__ void small_body(
    const u16* __restrict__ A, const u16* __restrict__ Bt,
    float* __restrict__ Cf, u16* __restrict__ Cb,
    const float* __restrict__ bias,
    int Nc, int K, int lda, int ldb, int outmode, int bshift,
    float kscale, float bmul, int bx, int by)
{
    __shared__ u16 lA[128 * 64];
    __shared__ u16 lB[128 * 64];
    const int tid = threadIdx.x;
    const int wave = tid >> 6, lane = tid & 63;
    const int l16 = lane & 15, lh = lane >> 4;
    const int wm = wave >> 1, wn = wave & 1;
    const long m0 = (long)bx * 128;
    const long n0 = (long)by * 128;

    f32x4 acc[4][4] = {};

    for (int k0 = 0; k0 < K; k0 += 64) {
#pragma unroll
        for (int j = 0; j < 4; ++j) {
            int c = j * 256 + tid;
            int row = c >> 3, col = (c & 7) << 3;
            g2l16(A  + (m0 + row) * (size_t)lda + k0 + col, &lA[(size_t)(j * 256 + (wave << 6)) * 8]);
            g2l16(Bt + (n0 + row) * (size_t)ldb + k0 + col, &lB[(size_t)(j * 256 + (wave << 6)) * 8]);
        }
        __syncthreads();
#pragma unroll
        for (int s = 0; s < 2; ++s) {
            bf16x8 af[4], bfr[4];
#pragma unroll
            for (int mi = 0; mi < 4; ++mi)
                af[mi] = *(const bf16x8*)&lA[((wm << 6) + (mi << 4) + l16) * 64 + s * 32 + (lh << 3)];
#pragma unroll
            for (int ni = 0; ni < 4; ++ni)
                bfr[ni] = *(const bf16x8*)&lB[((wn << 6) + (ni << 4) + l16) * 64 + s * 32 + (lh << 3)];
#pragma unroll
            for (int mi = 0; mi < 4; ++mi)
#pragma unroll
                for (int ni = 0; ni < 4; ++ni)
                    acc[mi][ni] = __builtin_amdgcn_mfma_f32_16x16x32_bf16(af[mi], bfr[ni], acc[mi][ni], 0, 0, 0);
        }
        __syncthreads();
    }

#pragma unroll
    for (int mi = 0; mi < 4; ++mi) {
#pragma unroll
        for (int ni = 0; ni < 4; ++ni) {
            long rbase = m0 + (wm << 6) + (mi << 4) + (lh << 2);
            long col   = n0 + (wn << 6) + (ni << 4) + l16;
#pragma unroll
            for (int r = 0; r < 4; ++r) {
                long row = rbase + r;
                float v = acc[mi][ni][r] * kscale;
                if (outmode == 2) {
                    v += (col < 1024 ? 1.0f : 256.0f / 255.0f) * bias[col & 1023];
                    Cb[(size_t)row * Nc + col] = f2bf(v);
                } else if (outmode == 3) {
                    if (bias) v += bmul * bias[(size_t)(row >> bshift) * Nc + col];
                    atomicAdd(&Cf[(size_t)row * Nc + col], v);
                } else {
                    if (bias) v += bmul * bias[(size_t)(row >> bshift) * Nc + col];
                    if (outmode == 1) Cf[(size_t)row * Nc + col] = v;
                    else              Cb[(size_t)row * Nc + col] = f2bf(v);
                }
            }
        }
    }
}

// S23 split-K: grid (8 k-chunks, 8 col-blocks); t12 += Acat[:,kc]@W2cat[:,kc]^T
// (+ b2 on k-chunk 0). t12 zero-initialized via hipMemsetAsync.
__global__ __launch_bounds__(256) void gemm_s23(
    const u16* __restrict__ Acat, const u16* __restrict__ W2cat,
    float* __restrict__ t12, const float* __restrict__ b2)
{
    small_body(Acat + blockIdx.x * 256, W2cat + blockIdx.x * 256, t12, nullptr,
               blockIdx.x == 0 ? b2 : nullptr,
               1024, 256, 2048, 2048, 3, 31, 1.0f, 1.0f, 0, blockIdx.y);
}

// Four independent small GEMMs in one launch (96 blocks)
__global__ __launch_bounds__(256) void k_small4(
    const u16* __restrict__ W2cat, const u16* __restrict__ W1rm, u16* __restrict__ W12t,
    const u16* __restrict__ W1bt, const u16* __restrict__ W1ab, u16* __restrict__ W1ct,
    const u16* __restrict__ W2bt, const u16* __restrict__ W2ab, u16* __restrict__ W2ct,
    const u16* __restrict__ s1b, const u16* __restrict__ Wcat, u16* __restrict__ Acat,
    const float* __restrict__ b1)
{
    const int bid = blockIdx.x;
    if (bid < 32) {
        small_body(W2cat, W1rm, nullptr, W12t, nullptr, 512, 1024, 2048, 1024,
                   0, 0, 1.0f, 0.0f, bid >> 2, bid & 3);
    } else if (bid < 64) {
        int r = bid - 32;
        small_body(W1bt, W1ab, nullptr, W1ct, nullptr, 1024, 1024, 1024, 1024,
                   0, 0, 1.0f, 0.0f, r >> 3, r & 7);
    } else if (bid < 80) {
        int r = bid - 64;
        small_body(W2bt, W2ab, nullptr, W2ct, nullptr, 256, 256, 256, 256,
                   0, 0, 1.0f, 0.0f, r >> 1, r & 1);
    } else {
        int r = bid - 80;
        small_body(s1b, Wcat, nullptr, Acat, b1, 2048, 512, 512, 512,
                   2, 0, 1.0f / 255.0f, 0.0f, 0, r);
    }
}

// ---------------------------------------------------------------------------
// Merged prep: weight transforms (blocks 0..2847) + x transpose/rowsum
// (blocks 2848..4895), one launch, all (32,8) = 256 threads.
// ---------------------------------------------------------------------------
__global__ __launch_bounds__(256) void k_prep(
    const float* __restrict__ Wl1, const float* __restrict__ Wr1,
    const float* __restrict__ Wl2, const float* __restrict__ Wr2,
    const float* __restrict__ W1b, const float* __restrict__ W2b,
    const float* __restrict__ W1a, const float* __restrict__ W2a,
    u16* __restrict__ Wcat, u16* __restrict__ W1rm,
    u16* __restrict__ W2cat,
    u16* __restrict__ W1bt, u16* __restrict__ W2bt,
    u16* __restrict__ W1ab, u16* __restrict__ W2ab,
    const float* __restrict__ x, u16* __restrict__ h, u16* __restrict__ s1b)
{
    __shared__ float smem[32 * 257];
    int bid = blockIdx.x;
    const int tx = threadIdx.x, ty = threadIdx.y;
    if (bid < 512) {
        float (*tl)[33] = (float(*)[33])smem;
        float (*tr)[33] = (float(*)[33])(smem + 32 * 33);
        int r0 = (bid >> 5) * 32, c0 = (bid & 31) * 32;
#pragma unroll
        for (int i = 0; i < 4; ++i) {
            int r = r0 + ty + 8 * i;
            float wl = Wl1[(size_t)r * H_ + c0 + tx];
            float wr = Wr1[(size_t)r * H_ + c0 + tx];
            tl[ty + 8 * i][tx] = wl;
            tr[ty + 8 * i][tx] = wl + wr;
            W1rm[(size_t)r * H_ + c0 + tx] = f2bf(wr - wl * (1.0f / 255.0f));
        }
        __syncthreads();
#pragma unroll
        for (int i = 0; i < 4; ++i) {
            size_t o = (size_t)(c0 + ty + 8 * i) * T_ + r0 + tx;
            Wcat[o]                     = f2bf(tl[tx][ty + 8 * i]);
            Wcat[o + (size_t)1024 * T_] = f2bf(tr[tx][ty + 8 * i]);
        }
    } else if (bid < 1536) {
        float (*tl)[33] = (float(*)[33])smem;
        float (*tr)[33] = (float(*)[33])(smem + 32 * 33);
        bid -= 512;
        int r0 = (bid >> 5) * 32, c0 = (bid & 31) * 32;
#pragma unroll
        for (int i = 0; i < 4; ++i) {
            int r = r0 + ty + 8 * i;
            float wl = Wl2[(size_t)r * H_ + c0 + tx];
            float wr = Wr2[(size_t)r * H_ + c0 + tx];
            tl[ty + 8 * i][tx] = wr - wl * (1.0f / 255.0f);
            tr[ty + 8 * i][tx] = wl;
        }
        __syncthreads();
#pragma unroll
        for (int i = 0; i < 4; ++i) {
            size_t o = (size_t)(c0 + ty + 8 * i) * 2048 + r0 + tx;
            W2cat[o]        = f2bf(tl[tx][ty + 8 * i]);
            W2cat[o + 1024] = f2bf(tr[tx][ty + 8 * i]);
        }
    } else if (bid < 2048) {
        float (*tl)[33] = (float(*)[33])smem;
        bid -= 1536;
        int r0 = (bid >> 4) * 32, c0 = (bid & 15) * 32;
#pragma unroll
        for (int i = 0; i < 4; ++i)
            tl[ty + 8 * i][tx] = W1b[(size_t)(r0 + ty + 8 * i) * T_ + c0 + tx];
        __syncthreads();
#pragma unroll
        for (int i = 0; i < 4; ++i)
            W1bt[(size_t)(c0 + ty + 8 * i) * H_ + r0 + tx] = f2bf(tl[tx][ty + 8 * i]);
    } else if (bid < 2304) {
        float (*tl)[33] = (float(*)[33])smem;
        bid -= 2048;
        int r0 = (bid >> 5) * 32, c0 = (bid & 31) * 32;
#pragma unroll
        for (int i = 0; i < 4; ++i)
            tl[ty + 8 * i][tx] = W2b[(size_t)(r0 + ty + 8 * i) * H_ + c0 + tx];
        __syncthreads();
#pragma unroll
        for (int i = 0; i < 4; ++i)
            W2bt[(size_t)(c0 + ty + 8 * i) * N_ + r0 + tx] = f2bf(tl[tx][ty + 8 * i]);
    } else if (bid < 2848) {
        int i = (bid - 2304) * 256 + ty * 32 + tx;
        const int n1 = H_ * H_ / 8;
        const float* s; u16* d;
        if (i < n1) { s = W1a; d = W1ab; }
        else        { s = W2a; d = W2ab; i -= n1; }
        float4 a = ((const float4*)s)[2 * i], b = ((const float4*)s)[2 * i + 1];
        u16 e[8] = {f2bf(a.x), f2bf(a.y), f2bf(a.z), f2bf(a.w),
                    f2bf(b.x), f2bf(b.y), f2bf(b.z), f2bf(b.w)};
        ((uint4*)d)[i] = *(const uint4*)e;
    } else {
        float (*sm)[257] = (float(*)[257])smem;
        int bid2 = bid - 2848;
        const int b = bid2 >> 4, t0 = (bid2 & 15) * 32;
        const int tid = ty * 32 + tx;
        const int wave = tid >> 6, lane = tid & 63;
        const float* xb = x + ((size_t)b * T_ + t0) * N_;
#pragma unroll
        for (int i = 0; i < 8; ++i) {
            int j = wave * 8 + i;
            float4 v = *(const float4*)(xb + (size_t)j * N_ + lane * 4);
            sm[j][lane * 4 + 0] = v.x;
            sm[j][lane * 4 + 1] = v.y;
            sm[j][lane * 4 + 2] = v.z;
            sm[j][lane * 4 + 3] = v.w;
        }
        __syncthreads();
#pragma unroll
        for (int i = 0; i < 8; ++i) {
            int j = wave * 8 + i;
            float s = sm[j][lane] + sm[j][lane + 64] + sm[j][lane + 128] + sm[j][lane + 192];
#pragma unroll
            for (int o = 32; o; o >>= 1) s += __shfl_down(s, o, 64);
            if (lane == 0) s1b[(size_t)b * T_ + t0 + j] = f2bf(s);
        }
        u16 e[32];
#pragma unroll
        for (int j = 0; j < 32; ++j) e[j] = f2bf(sm[j][tid]);
        uint4* dst = (uint4*)(h + ((size_t)b * N_ + tid) * T_ + t0);
        const uint4* src = (const uint4*)e;
#pragma unroll
        for (int v = 0; v < 4; ++v) dst[v] = src[v];
    }
}

extern "C" void kernel_launch(void* const* d_in, const int* in_sizes, int n_in,
                              void* d_out, int out_size, void* d_ws, size_t ws_size,
                              hipStream_t stream)
{
    const float* x   = (const float*)d_in[0];
    const float* Wl1 = (const float*)d_in[1];
    const float* Wr1 = (const float*)d_in[2];
    const float* b1  = (const float*)d_in[3];
    const float* Wl2 = (const float*)d_in[4];
    const float* Wr2 = (const float*)d_in[5];
    const float* b2  = (const float*)d_in[6];
    const float* W1a = (const float*)d_in[7];
    const float* W1b = (const float*)d_in[8];
    const float* W2a = (const float*)d_in[9];
    const float* W2b = (const float*)d_in[10];
    float* out = (float*)d_out;

    char* ws = (char*)d_ws;
    size_t off = 0;
    auto alloc = [&](size_t bytes) -> char* {
        char* p = ws + off;
        off += (bytes + 255) & ~(size_t)255;
        return p;
    };

    const size_t BN = (size_t)B_ * N_;   // 32768
    const size_t BT = (size_t)B_ * T_;   // 65536

    u16* h_bf   = (u16*)alloc(BN * T_ * 2);              // h, later q
    u16* h2_bf  = (u16*)alloc(BN * H_ * 2);
    u16* Wcat   = (u16*)alloc((size_t)2048 * T_ * 2);    // [Wl1t ; Wlr1t]
    u16* W1rm   = (u16*)alloc((size_t)T_ * H_ * 2);
    u16* W2cat  = (u16*)alloc((size_t)H_ * 2048 * 2);    // [W2'^T | Wl2^T]
    u16* W1bt   = (u16*)alloc((size_t)T_ * H_ * 2);
    u16* W1ab   = (u16*)alloc((size_t)H_ * H_ * 2);
    u16* W1ct   = (u16*)alloc((size_t)T_ * H_ * 2);
    u16* W2bt   = (u16*)alloc((size_t)H_ * N_ * 2);
    u16* W2ab   = (u16*)alloc((size_t)N_ * N_ * 2);
    u16* W2ct   = (u16*)alloc((size_t)H_ * N_ * 2);
    u16* W12t   = (u16*)alloc((size_t)H_ * T_ * 2);
    u16* s1b    = (u16*)alloc(BT * 2);
    u16* Acat   = (u16*)alloc((size_t)B_ * 2048 * 2);    // [t1b1 | u1s]
    float* t12  = (float*)alloc((size_t)B_ * H_ * 4);

    u16* q_bf = h_bf;

    // --- prep ---
    hipMemsetAsync(t12, 0, (size_t)B_ * H_ * 4, stream);
    k_prep<<<dim3(4896), dim3(32, 8), 0, stream>>>(Wl1, Wr1, Wl2, Wr2, W1b, W2b, W1a, W2a,
                                                   Wcat, W1rm, W2cat, W1bt, W2bt, W1ab, W2ab,
                                                   x, h_bf, s1b);
    k_small4<<<dim3(96), 256, 0, stream>>>(W2cat, W1rm, W12t, W1bt, W1ab, W1ct,
                                           W2bt, W2ab, W2ct, s1b, Wcat, Acat, b1);
    // S23 split-K: t12 += sum_kc Acat[:,kc]@W2cat[:,kc]^T (+ b2 on kc 0)
    gemm_s23<<<dim3(8, 8), 256, 0, stream>>>(Acat, W2cat, t12, b2);

    // --- main chain (3 e3 GEMMs; 2 blocks/CU) ---
    // GA: h2 = h @ W12 + t12   [32768,1024] K=512 -> 1024 wgs
    gemm_e3<0, 0><<<dim3(1024), 512, 0, stream>>>(h_bf, W12t, nullptr, h2_bf, t12, H_, T_, 8, 3);
    // GB: q = sigma(h2 @ W1c) transposed q[B,T,N], coalesced LDS epilogue
    gemm_e3<1, 2><<<dim3(512), 512, 0, stream>>>(h2_bf, W1ct, nullptr, q_bf, nullptr, T_, H_, 0, 2);
    // GC: out = sigma(q @ W2c) f32, nontemporal stores (write-once output)
    gemm_e3<1, 1><<<dim3(2048), 512, 0, stream>>>(q_bf, W2ct, out, nullptr, nullptr, H_, N_, 0, 3);
}